// Round 4
// baseline (291.615 us; speedup 1.0000x reference)
//
#include <hip/hip_runtime.h>
#include <hip/hip_bf16.h>
#include <float.h>

// B=4096, D=512, N=8192, temp=0.5
#define BN_ 4096
#define DD  512
#define NN  8192
#define SCALE 2.0f   // 1/temperature
#define NTILE 2080   // 64*65/2 lower-triangle 128x128 tiles
#define NDUTY 32     // last finishers run the fused lse

typedef unsigned short u16;
typedef __attribute__((ext_vector_type(8))) short short8;   // 8 bf16 = 4 VGPRs
typedef __attribute__((ext_vector_type(4))) float floatx4;  // MFMA acc

struct alignas(8) U16x4 { u16 x, y, z, w; };

__device__ __forceinline__ u16 f2bf(float f) {
    union { float f; unsigned u; } c; c.f = f;
    unsigned u = c.u;
    unsigned r = (u + 0x7fffu + ((u >> 16) & 1u)) >> 16;   // RNE
    return (u16)r;
}

__device__ __forceinline__ void async_copy16(const u16* g, u16* l) {
    __builtin_amdgcn_global_load_lds(
        (const __attribute__((address_space(1))) void*)g,
        (__attribute__((address_space(3))) void*)l, 16, 0, 0);
}

// ------ kernel 1: fp32 -> bf16 concat + per-block positive-dot partial ------
// block 0 zero-inits d_out and the gram ticket (harness poisons d_out).
__global__ __launch_bounds__(256) void convert_pos_kernel(const float* __restrict__ hi,
                                                          const float* __restrict__ hj,
                                                          u16* __restrict__ H,
                                                          float* __restrict__ Pos,
                                                          float* __restrict__ out,
                                                          unsigned* __restrict__ ticket) {
    __shared__ float red[4];
    int t = blockIdx.x * 256 + threadIdx.x;     // 2048 blocks -> 524288 threads
    int e = t * 4;
    const int BD = BN_ * DD;
    float4 a = *(const float4*)(hi + e);
    float4 b = *(const float4*)(hj + e);
    U16x4 oa, ob;
    oa.x = f2bf(a.x); oa.y = f2bf(a.y); oa.z = f2bf(a.z); oa.w = f2bf(a.w);
    ob.x = f2bf(b.x); ob.y = f2bf(b.y); ob.z = f2bf(b.z); ob.w = f2bf(b.w);
    *(U16x4*)(H + e) = oa;
    *(U16x4*)(H + BD + e) = ob;
    float dot = a.x * b.x + a.y * b.y + a.z * b.z + a.w * b.w;
#pragma unroll
    for (int msk = 1; msk < 64; msk <<= 1) dot += __shfl_xor(dot, msk);
    int lane = threadIdx.x & 63, wid = threadIdx.x >> 6;
    if (lane == 0) red[wid] = dot;
    __syncthreads();
    if (threadIdx.x == 0) {
        Pos[blockIdx.x] = red[0] + red[1] + red[2] + red[3];
        if (blockIdx.x == 0) { *out = 0.0f; *ticket = 0u; }
    }
}

// ------------- kernel 2: symmetric Gram, lower-triangle 128x128 tiles -------------
// EXACT round-0 K-loop structure (best measured: 63 us, MfmaUtil 22%): 4 waves as
// 2x2 of 64x64 wave tiles (4x4 of 16x16x32 bf16 MFMA), single-LDS-buffer 2-barrier
// K-loop, source-side XOR swizzle, conflict-free.  Round-4 deltas ONLY:
//  (a) LDS cut to exactly 32 KB (epilogue arrays alias onto As) + launch_bounds
//      (256,4): blocks/CU cap 4->5 for more stall cover (staging-rate hiding is
//      this structure's lever; intra-block pipelining measured neutral-to-bad).
//  (b) bijective XCD swizzle of the tile index (2080 = 8*260) for L2 locality.
//  (c) fused final LSE via ticketing (r3-proven protocol): last 32 finishers each
//      reduce 256 rows x 64 slots; saves the third launch (~7 us measured).
__global__ __launch_bounds__(256, 4) void gram_kernel(const u16* __restrict__ H,
                                                      float* __restrict__ Mpart,
                                                      float* __restrict__ Spart,
                                                      const float* __restrict__ Pos,
                                                      float* __restrict__ out,
                                                      unsigned* __restrict__ ticket) {
    __shared__ u16 As[128 * 64];    // 16 KB
    __shared__ u16 Bs[128 * 64];    // 16 KB   (total LDS = 32768 B exactly)

    // epilogue scratch aliases (used only after the K-loop's final barrier)
    float* Rm = (float*)&As[0];          // [2][128]
    float* Rs = Rm + 256;                // [2][128]
    float* Cm = Rs + 256;                // [2][128]
    float* Cs = Cm + 256;                // [2][128]
    unsigned* shT = (unsigned*)&Bs[0];   // ticket broadcast

    const int tid  = threadIdx.x;
    const int lane = tid & 63;
    const int wid  = tid >> 6;
    const int quad = lane >> 4;
    const int ln15 = lane & 15;
    const int wr = wid >> 1, wc = wid & 1;

    // bijective XCD swizzle (2080 % 8 == 0): consecutive tiles -> same XCD chunk
    int t = ((int)blockIdx.x & 7) * (NTILE / 8) + ((int)blockIdx.x >> 3);

    // lower-triangle decode: t in [0, 2080)
    int bi = (int)((sqrtf(8.0f * (float)t + 1.0f) - 1.0f) * 0.5f);
    while ((bi + 1) * (bi + 2) / 2 <= t) bi++;
    while (bi * (bi + 1) / 2 > t) bi--;
    const int bj = t - bi * (bi + 1) / 2;
    const bool diag = (bi == bj);
    const int biBase = bi * 128, bjBase = bj * 128;

    // staging pointers, hoisted (B source = A source + uniform delta)
    const u16* srcA[4];
    int ldsOff[4];
#pragma unroll
    for (int j = 0; j < 4; j++) {
        int c   = j * 256 + tid;        // chunk 0..1023
        int row = c >> 3;               // 0..127
        int kc  = (c & 7) ^ (row & 7);  // swizzle inverse on source side
        srcA[j]   = H + (size_t)(biBase + row) * DD + kc * 8;
        ldsOff[j] = c * 8;
    }
    const ptrdiff_t dB = (ptrdiff_t)(bjBase - biBase) * DD;

    floatx4 acc[4][4];
#pragma unroll
    for (int i = 0; i < 4; i++)
#pragma unroll
        for (int j = 0; j < 4; j++) acc[i][j] = (floatx4)0.0f;

    for (int k0 = 0; k0 < DD; k0 += 64) {
#pragma unroll
        for (int j = 0; j < 4; j++) async_copy16(srcA[j] + k0,      &As[ldsOff[j]]);
#pragma unroll
        for (int j = 0; j < 4; j++) async_copy16(srcA[j] + dB + k0, &Bs[ldsOff[j]]);
        __syncthreads();

#pragma unroll
        for (int kk = 0; kk < 2; kk++) {
            int ck = kk * 4 + quad;     // K-chunk 0..7 within the 64-wide tile
            short8 a[4], b[4];
#pragma unroll
            for (int tm = 0; tm < 4; tm++) {
                int r = wr * 64 + tm * 16 + ln15;
                a[tm] = *(const short8*)&As[(r * 8 + (ck ^ (r & 7))) * 8];
            }
#pragma unroll
            for (int tn = 0; tn < 4; tn++) {
                int r = wc * 64 + tn * 16 + ln15;
                b[tn] = *(const short8*)&Bs[(r * 8 + (ck ^ (r & 7))) * 8];
            }
#pragma unroll
            for (int tm = 0; tm < 4; tm++)
#pragma unroll
                for (int tn = 0; tn < 4; tn++)
                    acc[tm][tn] = __builtin_amdgcn_mfma_f32_16x16x32_bf16(
                        a[tm], b[tn], acc[tm][tn], 0, 0, 0);
        }
        __syncthreads();
    }

    // scale in place; mask self-similarity on diagonal tiles
    // C/D layout: local row = tm*16 + quad*4 + reg, local col = tn*16 + ln15
#pragma unroll
    for (int tm = 0; tm < 4; tm++)
#pragma unroll
        for (int tn = 0; tn < 4; tn++)
#pragma unroll
            for (int r = 0; r < 4; r++) {
                float v = SCALE * acc[tm][tn][r];
                if (diag) {
                    int lrow = wr * 64 + tm * 16 + quad * 4 + r;
                    int lcol = wc * 64 + tn * 16 + ln15;
                    if (lrow == lcol) v = -FLT_MAX;
                }
                acc[tm][tn][r] = v;
            }

    // row pass: per-row max+sumexp over this wave's 64 cols
#pragma unroll
    for (int tm = 0; tm < 4; tm++) {
#pragma unroll
        for (int r = 0; r < 4; r++) {
            float vmax = -FLT_MAX;
#pragma unroll
            for (int tn = 0; tn < 4; tn++) vmax = fmaxf(vmax, acc[tm][tn][r]);
#pragma unroll
            for (int msk = 1; msk < 16; msk <<= 1)
                vmax = fmaxf(vmax, __shfl_xor(vmax, msk));
            float s = 0.0f;
#pragma unroll
            for (int tn = 0; tn < 4; tn++) s += __expf(acc[tm][tn][r] - vmax);
#pragma unroll
            for (int msk = 1; msk < 16; msk <<= 1) s += __shfl_xor(s, msk);
            if (ln15 == 0) {
                int x = wr * 64 + tm * 16 + quad * 4 + r;
                Rm[wc * 128 + x] = vmax; Rs[wc * 128 + x] = s;
            }
        }
    }

    // col pass (transpose tile): per-col max+sumexp over this wave's 64 rows
    if (!diag) {
#pragma unroll
        for (int tn = 0; tn < 4; tn++) {
            float cm = -FLT_MAX;
#pragma unroll
            for (int tm = 0; tm < 4; tm++)
#pragma unroll
                for (int r = 0; r < 4; r++) cm = fmaxf(cm, acc[tm][tn][r]);
            cm = fmaxf(cm, __shfl_xor(cm, 16));
            cm = fmaxf(cm, __shfl_xor(cm, 32));
            float s = 0.0f;
#pragma unroll
            for (int tm = 0; tm < 4; tm++)
#pragma unroll
                for (int r = 0; r < 4; r++) s += __expf(acc[tm][tn][r] - cm);
            s += __shfl_xor(s, 16);
            s += __shfl_xor(s, 32);
            if (quad == 0) {
                int y = wc * 64 + tn * 16 + ln15;
                Cm[wr * 128 + y] = cm; Cs[wr * 128 + y] = s;
            }
        }
    }
    __syncthreads();

    // merge wave halves, write slot-major partials: Mpart[slot*NN + globalRow]
    if (tid < 128) {
        float m0 = Rm[tid], m1 = Rm[128 + tid];
        float s0 = Rs[tid], s1 = Rs[128 + tid];
        float m = fmaxf(m0, m1);
        float s = s0 * __expf(m0 - m) + s1 * __expf(m1 - m);
        Mpart[(size_t)bj * NN + biBase + tid] = m;
        Spart[(size_t)bj * NN + biBase + tid] = s;
    } else if (!diag) {
        int y = tid - 128;
        float m0 = Cm[y], m1 = Cm[128 + y];
        float s0 = Cs[y], s1 = Cs[128 + y];
        float m = fmaxf(m0, m1);
        float s = s0 * __expf(m0 - m) + s1 * __expf(m1 - m);
        Mpart[(size_t)bi * NN + bjBase + y] = m;
        Spart[(size_t)bi * NN + bjBase + y] = s;
    }

    // ---- publish + ticket; last NDUTY finishers run the fused LSE ----
    __threadfence();                       // release partials (device scope)
    __syncthreads();                       // all LDS epilogue reads done
    if (tid == 0) shT[0] = atomicAdd(ticket, 1u);
    __syncthreads();
    const unsigned myTicket = shT[0];
    if (myTicket >= (unsigned)(NTILE - NDUTY)) {
        if (tid == 0) {
            while (atomicAdd(ticket, 0u) < (unsigned)NTILE)
                __builtin_amdgcn_s_sleep(2);
        }
        __syncthreads();
        __threadfence();                   // acquire
        const int idx = (int)myTicket - (NTILE - NDUTY);   // 0..31
        int r = idx * 256 + tid;
        float m = -FLT_MAX, s = 0.0f;
#pragma unroll 8
        for (int c = 0; c < 64; c++) {
            float mc = Mpart[(size_t)c * NN + r];  // lane-contiguous, coalesced
            float sc = Spart[(size_t)c * NN + r];
            float mn = fmaxf(m, mc);
            s = s * __expf(m - mn) + sc * __expf(mc - mn);
            m = mn;
        }
        float v = m + logf(s);
        if (tid < 64) v += -4.0f * Pos[idx * 64 + tid];
        float* red = (float*)&As[0];
        red[tid] = v;
        __syncthreads();
        for (int st = 128; st > 0; st >>= 1) {
            if (tid < st) red[tid] += red[tid + st];
            __syncthreads();
        }
        if (tid == 0) atomicAdd(out, red[0] * (1.0f / (float)NN));
    }
}

extern "C" void kernel_launch(void* const* d_in, const int* in_sizes, int n_in,
                              void* d_out, int out_size, void* d_ws, size_t ws_size,
                              hipStream_t stream) {
    const float* hi = (const float*)d_in[0];
    const float* hj = (const float*)d_in[1];
    float* out = (float*)d_out;

    u16*      H      = (u16*)d_ws;                                          // 8 MB
    float*    Mpart  = (float*)((char*)d_ws + (size_t)8 * 1024 * 1024);     // 2 MB
    float*    Spart  = (float*)((char*)d_ws + (size_t)10 * 1024 * 1024);    // 2 MB
    float*    Pos    = (float*)((char*)d_ws + (size_t)12 * 1024 * 1024);    // 8 KB
    unsigned* ticket = (unsigned*)((char*)d_ws + (size_t)13 * 1024 * 1024); // 4 B

    convert_pos_kernel<<<2048, 256, 0, stream>>>(hi, hj, H, Pos, out, ticket);

    gram_kernel<<<NTILE, 256, 0, stream>>>(H, Mpart, Spart, Pos, out, ticket);
}

// Round 5
// 131.024 us; speedup vs baseline: 2.2257x; 2.2257x over previous
//
#include <hip/hip_runtime.h>
#include <hip/hip_bf16.h>
#include <float.h>

// B=4096, D=512, N=8192, temp=0.5
#define BN_ 4096
#define DD  512
#define NN  8192
#define SCALE 2.0f   // 1/temperature
#define NTILE 2080   // 64*65/2 lower-triangle 128x128 tiles

typedef unsigned short u16;
typedef __attribute__((ext_vector_type(8))) short short8;   // 8 bf16 = 4 VGPRs
typedef __attribute__((ext_vector_type(4))) float floatx4;  // MFMA acc

struct alignas(8) U16x4 { u16 x, y, z, w; };

__device__ __forceinline__ u16 f2bf(float f) {
    union { float f; unsigned u; } c; c.f = f;
    unsigned u = c.u;
    unsigned r = (u + 0x7fffu + ((u >> 16) & 1u)) >> 16;   // RNE
    return (u16)r;
}

__device__ __forceinline__ void async_copy16(const u16* g, u16* l) {
    __builtin_amdgcn_global_load_lds(
        (const __attribute__((address_space(1))) void*)g,
        (__attribute__((address_space(3))) void*)l, 16, 0, 0);
}

// ------ kernel 1: fp32 -> bf16 concat + per-block positive-dot partial ------
// NO atomics; each block plain-stores its partial to Pos[bid]; lse_kernel
// reduces them.  Block 0 zero-inits d_out (harness poisons it with 0xAA).
__global__ __launch_bounds__(256) void convert_pos_kernel(const float* __restrict__ hi,
                                                          const float* __restrict__ hj,
                                                          u16* __restrict__ H,
                                                          float* __restrict__ Pos,
                                                          float* __restrict__ out) {
    __shared__ float red[4];
    int t = blockIdx.x * 256 + threadIdx.x;     // 2048 blocks -> 524288 threads
    int e = t * 4;
    const int BD = BN_ * DD;
    float4 a = *(const float4*)(hi + e);
    float4 b = *(const float4*)(hj + e);
    U16x4 oa, ob;
    oa.x = f2bf(a.x); oa.y = f2bf(a.y); oa.z = f2bf(a.z); oa.w = f2bf(a.w);
    ob.x = f2bf(b.x); ob.y = f2bf(b.y); ob.z = f2bf(b.z); ob.w = f2bf(b.w);
    *(U16x4*)(H + e) = oa;
    *(U16x4*)(H + BD + e) = ob;
    float dot = a.x * b.x + a.y * b.y + a.z * b.z + a.w * b.w;
#pragma unroll
    for (int msk = 1; msk < 64; msk <<= 1) dot += __shfl_xor(dot, msk);
    int lane = threadIdx.x & 63, wid = threadIdx.x >> 6;
    if (lane == 0) red[wid] = dot;
    __syncthreads();
    if (threadIdx.x == 0) {
        Pos[blockIdx.x] = red[0] + red[1] + red[2] + red[3];
        if (blockIdx.x == 0) *out = 0.0f;
    }
}

// ------------- kernel 2: symmetric Gram, lower-triangle 128x128 tiles -------------
// EXACT round-0 K-loop (best measured: 63 us @ MfmaUtil 22%, bank-conflict 0).
// Round-5 deltas ONLY (fence/ticket fusion REMOVED -- r4 showed per-block
// __threadfence = full L2 wbl2+inv on gfx950, a ~170 us regression):
//  (a) LDS exactly 32 KB (epilogue arrays alias onto As) + __launch_bounds__(256,4)
//      -> 4 blocks/CU cap (r4 measured occupancy 25->35%): more TLP to hide the
//      staging stalls this structure is bound by.
//  (b) bijective XCD swizzle of the tile index (2080 = 8*260) for L2 locality.
__global__ __launch_bounds__(256, 4) void gram_kernel(const u16* __restrict__ H,
                                                      float* __restrict__ Mpart,
                                                      float* __restrict__ Spart) {
    __shared__ u16 As[128 * 64];    // 16 KB
    __shared__ u16 Bs[128 * 64];    // 16 KB   (total LDS = 32768 B exactly)

    // epilogue scratch aliases (used only after the K-loop's final barrier)
    float* Rm = (float*)&As[0];          // [2][128]
    float* Rs = Rm + 256;                // [2][128]
    float* Cm = Rs + 256;                // [2][128]
    float* Cs = Cm + 256;                // [2][128]

    const int tid  = threadIdx.x;
    const int lane = tid & 63;
    const int wid  = tid >> 6;
    const int quad = lane >> 4;
    const int ln15 = lane & 15;
    const int wr = wid >> 1, wc = wid & 1;

    // bijective XCD swizzle (2080 % 8 == 0): each XCD gets a contiguous tile chunk
    int t = ((int)blockIdx.x & 7) * (NTILE / 8) + ((int)blockIdx.x >> 3);

    // lower-triangle decode: t in [0, 2080)
    int bi = (int)((sqrtf(8.0f * (float)t + 1.0f) - 1.0f) * 0.5f);
    while ((bi + 1) * (bi + 2) / 2 <= t) bi++;
    while (bi * (bi + 1) / 2 > t) bi--;
    const int bj = t - bi * (bi + 1) / 2;
    const bool diag = (bi == bj);
    const int biBase = bi * 128, bjBase = bj * 128;

    // staging pointers, hoisted (B source = A source + uniform delta)
    const u16* srcA[4];
    int ldsOff[4];
#pragma unroll
    for (int j = 0; j < 4; j++) {
        int c   = j * 256 + tid;        // chunk 0..1023
        int row = c >> 3;               // 0..127
        int kc  = (c & 7) ^ (row & 7);  // swizzle inverse on source side
        srcA[j]   = H + (size_t)(biBase + row) * DD + kc * 8;
        ldsOff[j] = c * 8;
    }
    const ptrdiff_t dB = (ptrdiff_t)(bjBase - biBase) * DD;

    floatx4 acc[4][4];
#pragma unroll
    for (int i = 0; i < 4; i++)
#pragma unroll
        for (int j = 0; j < 4; j++) acc[i][j] = (floatx4)0.0f;

    for (int k0 = 0; k0 < DD; k0 += 64) {
#pragma unroll
        for (int j = 0; j < 4; j++) async_copy16(srcA[j] + k0,      &As[ldsOff[j]]);
#pragma unroll
        for (int j = 0; j < 4; j++) async_copy16(srcA[j] + dB + k0, &Bs[ldsOff[j]]);
        __syncthreads();

#pragma unroll
        for (int kk = 0; kk < 2; kk++) {
            int ck = kk * 4 + quad;     // K-chunk 0..7 within the 64-wide tile
            short8 a[4], b[4];
#pragma unroll
            for (int tm = 0; tm < 4; tm++) {
                int r = wr * 64 + tm * 16 + ln15;
                a[tm] = *(const short8*)&As[(r * 8 + (ck ^ (r & 7))) * 8];
            }
#pragma unroll
            for (int tn = 0; tn < 4; tn++) {
                int r = wc * 64 + tn * 16 + ln15;
                b[tn] = *(const short8*)&Bs[(r * 8 + (ck ^ (r & 7))) * 8];
            }
#pragma unroll
            for (int tm = 0; tm < 4; tm++)
#pragma unroll
                for (int tn = 0; tn < 4; tn++)
                    acc[tm][tn] = __builtin_amdgcn_mfma_f32_16x16x32_bf16(
                        a[tm], b[tn], acc[tm][tn], 0, 0, 0);
        }
        __syncthreads();
    }

    // scale in place; mask self-similarity on diagonal tiles
    // C/D layout: local row = tm*16 + quad*4 + reg, local col = tn*16 + ln15
#pragma unroll
    for (int tm = 0; tm < 4; tm++)
#pragma unroll
        for (int tn = 0; tn < 4; tn++)
#pragma unroll
            for (int r = 0; r < 4; r++) {
                float v = SCALE * acc[tm][tn][r];
                if (diag) {
                    int lrow = wr * 64 + tm * 16 + quad * 4 + r;
                    int lcol = wc * 64 + tn * 16 + ln15;
                    if (lrow == lcol) v = -FLT_MAX;
                }
                acc[tm][tn][r] = v;
            }

    // row pass: per-row max+sumexp over this wave's 64 cols
#pragma unroll
    for (int tm = 0; tm < 4; tm++) {
#pragma unroll
        for (int r = 0; r < 4; r++) {
            float vmax = -FLT_MAX;
#pragma unroll
            for (int tn = 0; tn < 4; tn++) vmax = fmaxf(vmax, acc[tm][tn][r]);
#pragma unroll
            for (int msk = 1; msk < 16; msk <<= 1)
                vmax = fmaxf(vmax, __shfl_xor(vmax, msk));
            float s = 0.0f;
#pragma unroll
            for (int tn = 0; tn < 4; tn++) s += __expf(acc[tm][tn][r] - vmax);
#pragma unroll
            for (int msk = 1; msk < 16; msk <<= 1) s += __shfl_xor(s, msk);
            if (ln15 == 0) {
                int x = wr * 64 + tm * 16 + quad * 4 + r;
                Rm[wc * 128 + x] = vmax; Rs[wc * 128 + x] = s;
            }
        }
    }

    // col pass (transpose tile): per-col max+sumexp over this wave's 64 rows
    if (!diag) {
#pragma unroll
        for (int tn = 0; tn < 4; tn++) {
            float cm = -FLT_MAX;
#pragma unroll
            for (int tm = 0; tm < 4; tm++)
#pragma unroll
                for (int r = 0; r < 4; r++) cm = fmaxf(cm, acc[tm][tn][r]);
            cm = fmaxf(cm, __shfl_xor(cm, 16));
            cm = fmaxf(cm, __shfl_xor(cm, 32));
            float s = 0.0f;
#pragma unroll
            for (int tm = 0; tm < 4; tm++)
#pragma unroll
                for (int r = 0; r < 4; r++) s += __expf(acc[tm][tn][r] - cm);
            s += __shfl_xor(s, 16);
            s += __shfl_xor(s, 32);
            if (quad == 0) {
                int y = wc * 64 + tn * 16 + ln15;
                Cm[wr * 128 + y] = cm; Cs[wr * 128 + y] = s;
            }
        }
    }
    __syncthreads();

    // merge wave halves, write slot-major partials: Mpart[slot*NN + globalRow]
    if (tid < 128) {
        float m0 = Rm[tid], m1 = Rm[128 + tid];
        float s0 = Rs[tid], s1 = Rs[128 + tid];
        float m = fmaxf(m0, m1);
        float s = s0 * __expf(m0 - m) + s1 * __expf(m1 - m);
        Mpart[(size_t)bj * NN + biBase + tid] = m;
        Spart[(size_t)bj * NN + biBase + tid] = s;
    } else if (!diag) {
        int y = tid - 128;
        float m0 = Cm[y], m1 = Cm[128 + y];
        float s0 = Cs[y], s1 = Cs[128 + y];
        float m = fmaxf(m0, m1);
        float s = s0 * __expf(m0 - m) + s1 * __expf(m1 - m);
        Mpart[(size_t)bi * NN + bjBase + y] = m;
        Spart[(size_t)bi * NN + bjBase + y] = s;
    }
}

// ------ kernel 3: combine 64 slot-partials per row + pos partials -> loss ------
// 128 blocks x 64 rows; each wave covers 16 slots of its 64 rows, merged in LDS.
__global__ __launch_bounds__(256) void lse_kernel(const float* __restrict__ Mpart,
                                                  const float* __restrict__ Spart,
                                                  const float* __restrict__ Pos,
                                                  float* __restrict__ out) {
    __shared__ float sm[4][64], ss[4][64];
    __shared__ float red[256];
    int tid = threadIdx.x;
    int wid = tid >> 6, lane = tid & 63;
    int r = blockIdx.x * 64 + lane;
    float m = -FLT_MAX, s = 0.0f;
#pragma unroll
    for (int i = 0; i < 16; i++) {
        int c = wid * 16 + i;
        float mc = Mpart[(size_t)c * NN + r];   // coalesced: lane-stride 4B
        float sc = Spart[(size_t)c * NN + r];
        float mn = fmaxf(m, mc);
        s = s * __expf(m - mn) + sc * __expf(mc - mn);
        m = mn;
    }
    sm[wid][lane] = m; ss[wid][lane] = s;
    __syncthreads();
    float v = 0.0f;
    if (tid < 64) {
        float m0 = sm[0][tid], m1 = sm[1][tid], m2 = sm[2][tid], m3 = sm[3][tid];
        float mm = fmaxf(fmaxf(m0, m1), fmaxf(m2, m3));
        float sa = ss[0][tid] * __expf(m0 - mm) + ss[1][tid] * __expf(m1 - mm)
                 + ss[2][tid] * __expf(m2 - mm) + ss[3][tid] * __expf(m3 - mm);
        v = mm + logf(sa);
        if (tid < 16) v += -4.0f * Pos[blockIdx.x * 16 + tid];
    }
    red[tid] = v;
    __syncthreads();
    for (int st = 128; st > 0; st >>= 1) {
        if (tid < st) red[tid] += red[tid + st];
        __syncthreads();
    }
    if (tid == 0) atomicAdd(out, red[0] * (1.0f / (float)NN));
}

extern "C" void kernel_launch(void* const* d_in, const int* in_sizes, int n_in,
                              void* d_out, int out_size, void* d_ws, size_t ws_size,
                              hipStream_t stream) {
    const float* hi = (const float*)d_in[0];
    const float* hj = (const float*)d_in[1];
    float* out = (float*)d_out;

    u16*   H     = (u16*)d_ws;                                            // 8 MB
    float* Mpart = (float*)((char*)d_ws + (size_t)8 * 1024 * 1024);       // 2 MB
    float* Spart = (float*)((char*)d_ws + (size_t)10 * 1024 * 1024);      // 2 MB
    float* Pos   = (float*)((char*)d_ws + (size_t)12 * 1024 * 1024);      // 8 KB

    convert_pos_kernel<<<2048, 256, 0, stream>>>(hi, hj, H, Pos, out);

    gram_kernel<<<NTILE, 256, 0, stream>>>(H, Mpart, Spart);

    lse_kernel<<<128, 256, 0, stream>>>(Mpart, Spart, Pos, out);
}